// Round 4
// baseline (760.276 us; speedup 1.0000x reference)
//
#include <hip/hip_runtime.h>
#include <stdint.h>

#define QLEN  2048
#define PAST  2048
#define D_    2048
#define B_    4
#define LK    4096   // PAST + QLEN

typedef unsigned short ushort_t;
typedef __bf16  bf16x8 __attribute__((ext_vector_type(8)));
typedef float   f32x4  __attribute__((ext_vector_type(4)));

#define AS1 __attribute__((address_space(1)))
#define AS3 __attribute__((address_space(3)))

__device__ __forceinline__ ushort_t f2bf(float f) {
  union { float f; uint32_t u; } v; v.f = f;
  uint32_t u = v.u;
  u += 0x7FFFu + ((u >> 16) & 1u);   // RNE
  return (ushort_t)(u >> 16);
}

// ---------------- diagnostic fallback (ws too small) ----------------
__global__ __launch_bounds__(256) void diag_fill(float* __restrict__ out, int n4, float v0) {
  int i = blockIdx.x * 256 + threadIdx.x;
  if (i >= n4) return;
  float4 z = make_float4(0.f, 0.f, 0.f, 0.f);
  if (i == 0) z.x = v0;
  ((float4*)out)[i] = z;
}

// ---------------- fp32 -> bf16 cast ----------------
__global__ __launch_bounds__(256) void cast_f32_bf16(const float* __restrict__ src,
                                                     ushort_t* __restrict__ dst, int n4) {
  int i = blockIdx.x * 256 + threadIdx.x;
  if (i >= n4) return;
  float4 v = ((const float4*)src)[i];
  ushort4 o; o.x = f2bf(v.x); o.y = f2bf(v.y); o.z = f2bf(v.z); o.w = f2bf(v.w);
  ((ushort4*)dst)[i] = o;
}

// ---------------- fp32 [PAST][D] -> bf16 [D][PAST] transpose-cast, z-batched --------
__global__ __launch_bounds__(256) void transpose_cast(const float* __restrict__ src0,
                                                      ushort_t* __restrict__ dst0,
                                                      size_t sbs, size_t dbs) {
  __shared__ float tile[64][65];
  const float* src = src0 + (size_t)blockIdx.z * sbs;
  ushort_t* dst = dst0 + (size_t)blockIdx.z * dbs;
  const int r0 = blockIdx.x * 64, c0 = blockIdx.y * 64;   // r: past index, c: d index
  const int tid = threadIdx.x;
  const int rr = tid >> 4, cc = (tid & 15) * 4;
  #pragma unroll
  for (int it = 0; it < 4; ++it) {
    int r = rr + it * 16;
    float4 v = *(const float4*)(src + (size_t)(r0 + r) * D_ + c0 + cc);
    tile[r][cc] = v.x; tile[r][cc + 1] = v.y; tile[r][cc + 2] = v.z; tile[r][cc + 3] = v.w;
  }
  __syncthreads();
  const int cw = tid >> 4, rw = (tid & 15) * 4;
  #pragma unroll
  for (int it = 0; it < 4; ++it) {
    int c = cw + it * 16;
    ushort4 o;
    o.x = f2bf(tile[rw][c]);     o.y = f2bf(tile[rw + 1][c]);
    o.z = f2bf(tile[rw + 2][c]); o.w = f2bf(tile[rw + 3][c]);
    *(ushort4*)(dst + (size_t)(c0 + c) * PAST + r0 + rw) = o;
  }
}

// ---------------- unified GEMM: C = A[M,K] * B^T, bf16 in, fp32 acc ----------------
// 256x256 tile, 512 threads (8 waves, 2M x 4N), mfma_f32_16x16x32_bf16.
// K pipelined as a 5-SLOT ring of K=32 sub-tiles (A[256][32]+B[256][32] per
// slot, 160 KiB LDS -- full CU LDS, still 1 block/CU as before). Fragment
// reads run ONE SUB-TILE AHEAD in registers; staging runs FOUR ahead:
//   iter u: read a47(u) | stage(u+4) | MFMA a03xB(u) | read a03(u+1),B(u+1) |
//           MFMA a47xB(u) | sched_barrier; vmcnt; s_barrier; sched_barrier
// Boundary end-of-u waits vmcnt(8): retires stage(u+2) -- issued TWO
// iterations earlier (ample slack for L2/HBM latency; round-3's 4-slot ring
// forced vmcnt(4) = 1-iteration slack and stalled every boundary). This
// publishes slot u+2 exactly when iter u+1's mid-iteration pre-reads need it.
// WAR: every ds_read of a slot is lgkm-drained by the MFMAs that consume it
// >=1 barrier before that slot's overwriting stage is issued (ring of 5).
// Tail: u+4==NU -> vmcnt(4); u+4>NU -> vmcnt(0).
// LDS 16B-part swizzle: physical part p of row r holds global part p ^ ((r>>1)&3),
// applied by pre-swizzling the GLOBAL source (global_load_lds dest stays linear).
// SEG2: B rows come from B0 for k < Kseg, else B1 (same ldb); Kseg % 32 == 0.
struct GZ  { const ushort_t* A; const ushort_t* B0; const ushort_t* B1; void* C; };
struct GZV { GZ z[12]; };

template <bool OUT_BF16, bool SEG2>
__global__ __launch_bounds__(512, 2) void gemm_bt(GZV gz, int lda, int ldb, int K, int Kseg,
                                                  int ldc, float scale) {
  __shared__ ushort_t As[5][256 * 32];   // 5 x 16 KiB
  __shared__ ushort_t Bs[5][256 * 32];   // 5 x 16 KiB  (total 160 KiB)
  const GZ g = gz.z[blockIdx.z];

  const int tid  = threadIdx.x;
  const int lane = tid & 63;
  const int wave = tid >> 6;
  const int wm = wave >> 2, wn = wave & 3;           // 2 x 4 wave grid
  const int m0 = blockIdx.y * 256, n0 = blockIdx.x * 256;

  // ---- staging invariants: 1024 chunks of 16B per matrix per sub-tile,
  //      2 rounds of 512 threads. chunk c = tid + j*512: row c>>2, phys part c&3.
  const int r0s = tid >> 2;                          // 0..127 (round 0); round1 = +128
  const int pgs = (tid & 3) ^ ((r0s >> 1) & 3);      // global part (swizzle involution)
  const ushort_t* gA  = g.A  + (size_t)(m0 + r0s) * lda + pgs * 8;
  const ushort_t* gB0 = g.B0 + (size_t)(n0 + r0s) * ldb + pgs * 8;
  const ushort_t* gB1 = SEG2 ? (g.B1 + (size_t)(n0 + r0s) * ldb + pgs * 8) : gB0;
  const size_t rstepA = (size_t)128 * lda;
  const size_t rstepB = (size_t)128 * ldb;
  const int ldsOff = tid * 8;                        // ushort units; 16B per thread

  // ---- loop-invariant fragment read offsets (ushort units)
  const int laneRow = lane & 15, quad = lane >> 4;
  int offA[8], offB[4];
  #pragma unroll
  for (int mi = 0; mi < 8; ++mi) {
    const int row = wm * 128 + mi * 16 + laneRow;
    offA[mi] = row * 32 + ((quad ^ ((row >> 1) & 3)) * 8);
  }
  #pragma unroll
  for (int ni = 0; ni < 4; ++ni) {
    const int row = wn * 64 + ni * 16 + laneRow;
    offB[ni] = row * 32 + ((quad ^ ((row >> 1) & 3)) * 8);
  }

  const int NU = K >> 5;   // number of K=32 sub-tiles (always even here)

  auto stageA = [&](int u) {
    const int k0 = u << 5;
    ushort_t* dst = &As[u % 5][0];
    __builtin_amdgcn_global_load_lds((const AS1 uint32_t*)(gA + k0),
                                     (AS3 uint32_t*)(dst + ldsOff), 16, 0, 0);
    __builtin_amdgcn_global_load_lds((const AS1 uint32_t*)(gA + rstepA + k0),
                                     (AS3 uint32_t*)(dst + 4096 + ldsOff), 16, 0, 0);
  };
  auto stageB = [&](int u) {
    const int k0 = u << 5;
    ushort_t* dst = &Bs[u % 5][0];
    const ushort_t* src = gB0;
    int kk = k0;
    if (SEG2 && k0 >= Kseg) { src = gB1; kk = k0 - Kseg; }
    __builtin_amdgcn_global_load_lds((const AS1 uint32_t*)(src + kk),
                                     (AS3 uint32_t*)(dst + ldsOff), 16, 0, 0);
    __builtin_amdgcn_global_load_lds((const AS1 uint32_t*)(src + rstepB + kk),
                                     (AS3 uint32_t*)(dst + 4096 + ldsOff), 16, 0, 0);
  };

  f32x4 acc[8][4] = {};

  // ---- prologue: stage sub-tiles 0..3 (16 loads); vmcnt(8) -> slots 0,1 published
  stageA(0); stageB(0);
  stageA(1); stageB(1);
  stageA(2); stageB(2);
  stageA(3); stageB(3);
  __builtin_amdgcn_sched_barrier(0);
  asm volatile("s_waitcnt vmcnt(8)" ::: "memory");
  __builtin_amdgcn_s_barrier();
  __builtin_amdgcn_sched_barrier(0);

  // pre-read first-half A and B of sub-tile 0
  bf16x8 a03[4], a47[4], bA[4], bB[4];
  #pragma unroll
  for (int mi = 0; mi < 4; ++mi) a03[mi] = *(const bf16x8*)(&As[0][0] + offA[mi]);
  #pragma unroll
  for (int ni = 0; ni < 4; ++ni) bA[ni] = *(const bf16x8*)(&Bs[0][0] + offB[ni]);

  for (int u = 0; u < NU; u += 2) {
    // ================= even iteration u (current B in bA) =================
    {
      const ushort_t* Au = &As[u % 5][0];
      const ushort_t* An = &As[(u + 1) % 5][0];
      const ushort_t* Bn = &Bs[(u + 1) % 5][0];

      #pragma unroll
      for (int mi = 0; mi < 4; ++mi) a47[mi] = *(const bf16x8*)(Au + offA[4 + mi]);
      if (u + 4 < NU) { stageA(u + 4); stageB(u + 4); }

      __builtin_amdgcn_s_setprio(1);
      #pragma unroll
      for (int mi = 0; mi < 4; ++mi)
        #pragma unroll
        for (int ni = 0; ni < 4; ++ni)
          acc[mi][ni] = __builtin_amdgcn_mfma_f32_16x16x32_bf16(a03[mi], bA[ni], acc[mi][ni], 0, 0, 0);
      __builtin_amdgcn_s_setprio(0);

      // pre-read sub-tile u+1 (slot published by boundary end-of-(u-1))
      #pragma unroll
      for (int mi = 0; mi < 4; ++mi) a03[mi] = *(const bf16x8*)(An + offA[mi]);
      #pragma unroll
      for (int ni = 0; ni < 4; ++ni) bB[ni] = *(const bf16x8*)(Bn + offB[ni]);

      __builtin_amdgcn_s_setprio(1);
      #pragma unroll
      for (int mi = 0; mi < 4; ++mi)
        #pragma unroll
        for (int ni = 0; ni < 4; ++ni)
          acc[4 + mi][ni] = __builtin_amdgcn_mfma_f32_16x16x32_bf16(a47[mi], bA[ni], acc[4 + mi][ni], 0, 0, 0);
      __builtin_amdgcn_s_setprio(0);

      __builtin_amdgcn_sched_barrier(0);
      if (u + 4 < NU)       { asm volatile("s_waitcnt vmcnt(8)" ::: "memory"); }
      else if (u + 4 == NU) { asm volatile("s_waitcnt vmcnt(4)" ::: "memory"); }
      else                  { asm volatile("s_waitcnt vmcnt(0)" ::: "memory"); }
      __builtin_amdgcn_s_barrier();
      __builtin_amdgcn_sched_barrier(0);
    }
    // ================= odd iteration u+1 (current B in bB) =================
    {
      const int uo = u + 1;
      const ushort_t* Au = &As[uo % 5][0];
      const ushort_t* An = &As[(uo + 1) % 5][0];   // tail: garbage-read is harmless
      const ushort_t* Bn = &Bs[(uo + 1) % 5][0];   // (valid LDS, values unused)

      #pragma unroll
      for (int mi = 0; mi < 4; ++mi) a47[mi] = *(const bf16x8*)(Au + offA[4 + mi]);
      if (uo + 4 < NU) { stageA(uo + 4); stageB(uo + 4); }

      __builtin_amdgcn_s_setprio(1);
      #pragma unroll
      for (int mi = 0; mi < 4; ++mi)
        #pragma unroll
        for (int ni = 0; ni < 4; ++ni)
          acc[mi][ni] = __builtin_amdgcn_mfma_f32_16x16x32_bf16(a03[mi], bB[ni], acc[mi][ni], 0, 0, 0);
      __builtin_amdgcn_s_setprio(0);

      #pragma unroll
      for (int mi = 0; mi < 4; ++mi) a03[mi] = *(const bf16x8*)(An + offA[mi]);
      #pragma unroll
      for (int ni = 0; ni < 4; ++ni) bA[ni] = *(const bf16x8*)(Bn + offB[ni]);

      __builtin_amdgcn_s_setprio(1);
      #pragma unroll
      for (int mi = 0; mi < 4; ++mi)
        #pragma unroll
        for (int ni = 0; ni < 4; ++ni)
          acc[4 + mi][ni] = __builtin_amdgcn_mfma_f32_16x16x32_bf16(a47[mi], bB[ni], acc[4 + mi][ni], 0, 0, 0);
      __builtin_amdgcn_s_setprio(0);

      __builtin_amdgcn_sched_barrier(0);
      if (uo + 4 < NU)       { asm volatile("s_waitcnt vmcnt(8)" ::: "memory"); }
      else if (uo + 4 == NU) { asm volatile("s_waitcnt vmcnt(4)" ::: "memory"); }
      else                   { asm volatile("s_waitcnt vmcnt(0)" ::: "memory"); }
      __builtin_amdgcn_s_barrier();
      __builtin_amdgcn_sched_barrier(0);
    }
  }

  // ---- epilogue: C/D layout col = lane&15, row = (lane>>4)*4 + reg
  const int col = lane & 15;
  #pragma unroll
  for (int mi = 0; mi < 8; ++mi) {
    #pragma unroll
    for (int ni = 0; ni < 4; ++ni) {
      const int n = n0 + wn * 64 + ni * 16 + col;
      const int mb = m0 + wm * 128 + mi * 16 + quad * 4;
      #pragma unroll
      for (int r = 0; r < 4; ++r) {
        const int m = mb + r;
        const float v = acc[mi][ni][r] * scale;
        if constexpr (OUT_BF16)
          ((ushort_t*)g.C)[(size_t)m * ldc + n] = f2bf(v);
        else
          ((float*)g.C)[(size_t)m * ldc + n] = v;
      }
    }
  }
}

// ---------------- in-place row softmax on bf16 S [rows][4096], two buffers ----------
__global__ __launch_bounds__(256) void softmax_inplace(ushort_t* __restrict__ Sa,
                                                       ushort_t* __restrict__ Sb) {
  ushort_t* S = blockIdx.y ? Sb : Sa;
  const int row = blockIdx.x, tid = threadIdx.x;
  const int lane = tid & 63, wave = tid >> 6;
  ushort_t* s = S + (size_t)row * LK;

  float e[16];
  float m = -1e30f;
  #pragma unroll
  for (int i = 0; i < 2; ++i) {
    uint4 raw = *(const uint4*)(s + i * 2048 + tid * 8);
    const uint32_t u[4] = { raw.x, raw.y, raw.z, raw.w };
    #pragma unroll
    for (int j = 0; j < 4; ++j) {
      union { uint32_t u; float f; } lo, hi;
      lo.u = u[j] << 16;
      hi.u = u[j] & 0xFFFF0000u;
      e[i * 8 + j * 2] = lo.f;
      e[i * 8 + j * 2 + 1] = hi.f;
      m = fmaxf(m, fmaxf(lo.f, hi.f));
    }
  }
  #pragma unroll
  for (int off = 32; off > 0; off >>= 1) m = fmaxf(m, __shfl_xor(m, off));
  __shared__ float redm[4], reds[4];
  if (lane == 0) redm[wave] = m;
  __syncthreads();
  m = fmaxf(fmaxf(redm[0], redm[1]), fmaxf(redm[2], redm[3]));

  float sum = 0.f;
  #pragma unroll
  for (int i = 0; i < 16; ++i) { e[i] = __expf(e[i] - m); sum += e[i]; }
  #pragma unroll
  for (int off = 32; off > 0; off >>= 1) sum += __shfl_xor(sum, off);
  if (lane == 0) reds[wave] = sum;
  __syncthreads();
  sum = reds[0] + reds[1] + reds[2] + reds[3];
  const float inv = 1.0f / sum;

  #pragma unroll
  for (int i = 0; i < 2; ++i) {
    uint4 o;
    uint32_t* po = &o.x;
    #pragma unroll
    for (int j = 0; j < 4; ++j) {
      uint32_t lo = f2bf(e[i * 8 + j * 2] * inv);
      uint32_t hi = f2bf(e[i * 8 + j * 2 + 1] * inv);
      po[j] = lo | (hi << 16);
    }
    *(uint4*)(s + i * 2048 + tid * 8) = o;
  }
}

// ---------------- launch ----------------
extern "C" void kernel_launch(void* const* d_in, const int* in_sizes, int n_in,
                              void* d_out, int out_size, void* d_ws, size_t ws_size,
                              hipStream_t stream) {
  const float* x      = (const float*)d_in[0];
  const float* past_k = (const float*)d_in[1];
  const float* past_v = (const float*)d_in[2];
  const float* Wq     = (const float*)d_in[3];
  const float* Wk     = (const float*)d_in[4];
  const float* Wv     = (const float*)d_in[5];
  float* out = (float*)d_out;

  const size_t MB = 1024 * 1024;
  const size_t NEED = 160 * MB;
  if (ws_size < NEED) {
    diag_fill<<<(out_size / 4 + 255) / 256, 256, 0, stream>>>(out, out_size / 4,
                                                              (float)((double)ws_size * 1e-9));
    return;
  }

  char* ws = (char*)d_ws;
  // Layout (MB):
  //   0-16  : Q pair0 (b0@0, b1@8)         [dead after S-gemm pair0]
  //  16-32  : Knew pair0 (b0@16, b1@24)    [dead after S-gemm pair0]
  //  32-48  : Q pair1 (b2@32, b3@40)       [dead after S-gemm pair1]
  //  48-64  : Knew pair1 (b2@48, b3@56)    [dead after S-gemm pair1]
  //  64-96  : VTnew all (b@64+8b), [D][QLEN]
  //  96-160 : scratch:
  //     phase A : xb@96 (32), Wq@128, Wk@136, Wv@144
  //     then    : Kp all @96 (32, [PAST][D] per b)
  //     then    : S0 (pair0) @128 (32, bf16 [4096][4096])
  //     then    : S1 (pair1) @0   (32, over dead Q/Kn pair0)
  //     then    : VTp all @96 (32, [D][PAST] per b, over dead Kp)
  ushort_t* Qp[4]  = { (ushort_t*)(ws),            (ushort_t*)(ws + 8  * MB),
                       (ushort_t*)(ws + 32 * MB),  (ushort_t*)(ws + 40 * MB) };
  ushort_t* Knp[4] = { (ushort_t*)(ws + 16 * MB),  (ushort_t*)(ws + 24 * MB),
                       (ushort_t*)(ws + 48 * MB),  (ushort_t*)(ws + 56 * MB) };
  ushort_t* VTn = (ushort_t*)(ws + 64 * MB);   // + b*8MB
  ushort_t* xb  = (ushort_t*)(ws + 96 * MB);   // + b*8MB
  ushort_t* Wqb = (ushort_t*)(ws + 128 * MB);
  ushort_t* Wkb = (ushort_t*)(ws + 136 * MB);
  ushort_t* Wvb = (ushort_t*)(ws + 144 * MB);
  ushort_t* Kp  = (ushort_t*)(ws + 96 * MB);   // + b*8MB (after xb dead)
  ushort_t* S0  = (ushort_t*)(ws + 128 * MB);  // rows 0-2047: b0, 2048-4095: b1
  ushort_t* S1  = (ushort_t*)(ws);             // rows 0-2047: b2, 2048-4095: b3
  ushort_t* VTp = (ushort_t*)(ws + 96 * MB);   // + b*8MB (after Kp dead)

  const size_t SLICE = (size_t)QLEN * D_;      // 4M elements = 8 MB bf16

  // ---- phase A: casts ----
  cast_f32_bf16<<<(B_ * SLICE / 4) / 256, 256, 0, stream>>>(x, xb, B_ * SLICE / 4);
  cast_f32_bf16<<<(D_ * D_ / 4) / 256, 256, 0, stream>>>(Wq, Wqb, D_ * D_ / 4);
  cast_f32_bf16<<<(D_ * D_ / 4) / 256, 256, 0, stream>>>(Wk, Wkb, D_ * D_ / 4);
  cast_f32_bf16<<<(D_ * D_ / 4) / 256, 256, 0, stream>>>(Wv, Wvb, D_ * D_ / 4);

  // ---- all projections in one Z=12 launch: Q, Knew, VTnew ----
  {
    GZV g{};
    for (int b = 0; b < B_; ++b) {
      const ushort_t* xbb = xb + (size_t)b * SLICE;
      g.z[b]     = { xbb, Wqb, Wqb, Qp[b] };                      // Q_b [t][d]
      g.z[4 + b] = { xbb, Wkb, Wkb, Knp[b] };                     // Kn_b [t][d]
      g.z[8 + b] = { Wvb, xbb, xbb, VTn + (size_t)b * SLICE };    // VTn_b [d][t]
    }
    gemm_bt<true, false><<<dim3(8, 8, 12), 512, 0, stream>>>(g, D_, D_, D_, D_, D_, 1.0f);
  }

  // ---- cast past_k (all batches) ----
  cast_f32_bf16<<<(B_ * (size_t)PAST * D_ / 4) / 256, 256, 0, stream>>>(
      past_k, Kp, B_ * PAST * D_ / 4);

  const float sc = 0.022097086912079608f;  // 1/sqrt(2048)

  // ---- S pair0 (b0,b1): Z=4, bf16 out into S0 ----
  {
    GZV g{};
    for (int j = 0; j < 2; ++j) {
      const int b = j;
      ushort_t* Sb = S0 + (size_t)j * QLEN * LK;
      g.z[2 * j]     = { Qp[b], Kp + (size_t)b * SLICE,  Kp + (size_t)b * SLICE,  Sb };
      g.z[2 * j + 1] = { Qp[b], Knp[b],                  Knp[b],                  Sb + PAST };
    }
    gemm_bt<true, false><<<dim3(8, 8, 4), 512, 0, stream>>>(g, D_, D_, D_, D_, LK, sc);
  }
  // ---- S pair1 (b2,b3): Z=4, bf16 out into S1 (over dead Q/Kn pair0) ----
  {
    GZV g{};
    for (int j = 0; j < 2; ++j) {
      const int b = 2 + j;
      ushort_t* Sb = S1 + (size_t)j * QLEN * LK;
      g.z[2 * j]     = { Qp[b], Kp + (size_t)b * SLICE,  Kp + (size_t)b * SLICE,  Sb };
      g.z[2 * j + 1] = { Qp[b], Knp[b],                  Knp[b],                  Sb + PAST };
    }
    gemm_bt<true, false><<<dim3(8, 8, 4), 512, 0, stream>>>(g, D_, D_, D_, D_, LK, sc);
  }

  // ---- transpose-cast past_v (all batches) into VTp (over dead Kp) ----
  transpose_cast<<<dim3(PAST / 64, D_ / 64, B_), 256, 0, stream>>>(
      past_v, VTp, (size_t)PAST * D_, (size_t)D_ * PAST);

  // ---- softmax in place on S0 and S1 ----
  softmax_inplace<<<dim3(2 * QLEN, 2), 256, 0, stream>>>(S0, S1);

  // ---- PV: Z=4, 2-segment K (VTp then VTn), fp32 out to d_out ----
  {
    GZV g{};
    const ushort_t* Pb[4] = { S0, S0 + (size_t)QLEN * LK, S1, S1 + (size_t)QLEN * LK };
    for (int b = 0; b < B_; ++b)
      g.z[b] = { Pb[b], VTp + (size_t)b * SLICE, VTn + (size_t)b * SLICE,
                 out + (size_t)b * QLEN * D_ };
    gemm_bt<false, true><<<dim3(8, 8, 4), 512, 0, stream>>>(g, LK, PAST, LK, PAST, D_, 1.0f);
  }
}

// Round 5
// 688.233 us; speedup vs baseline: 1.1047x; 1.1047x over previous
//
#include <hip/hip_runtime.h>
#include <stdint.h>

#define QLEN  2048
#define PAST  2048
#define D_    2048
#define B_    4
#define LK    4096   // PAST + QLEN

typedef unsigned short ushort_t;
typedef __bf16  bf16x8 __attribute__((ext_vector_type(8)));
typedef float   f32x4  __attribute__((ext_vector_type(4)));

#define AS1 __attribute__((address_space(1)))
#define AS3 __attribute__((address_space(3)))

__device__ __forceinline__ ushort_t f2bf(float f) {
  union { float f; uint32_t u; } v; v.f = f;
  uint32_t u = v.u;
  u += 0x7FFFu + ((u >> 16) & 1u);   // RNE
  return (ushort_t)(u >> 16);
}

// ---------------- diagnostic fallback (ws too small) ----------------
__global__ __launch_bounds__(256) void diag_fill(float* __restrict__ out, int n4, float v0) {
  int i = blockIdx.x * 256 + threadIdx.x;
  if (i >= n4) return;
  float4 z = make_float4(0.f, 0.f, 0.f, 0.f);
  if (i == 0) z.x = v0;
  ((float4*)out)[i] = z;
}

// ---------------- fp32 -> bf16 cast (used for past_k) ----------------
__global__ __launch_bounds__(256) void cast_f32_bf16(const float* __restrict__ src,
                                                     ushort_t* __restrict__ dst, int n4) {
  int i = blockIdx.x * 256 + threadIdx.x;
  if (i >= n4) return;
  float4 v = ((const float4*)src)[i];
  ushort4 o; o.x = f2bf(v.x); o.y = f2bf(v.y); o.z = f2bf(v.z); o.w = f2bf(v.w);
  ((ushort4*)dst)[i] = o;
}

// ---------------- merged phase-A cast: x, Wq, Wk, Wv in one launch ----------------
// x = 4*2^20 float4s, each W = 2^20 float4s -> segment pick is two shifts.
__global__ __launch_bounds__(256) void cast_pre(const float* __restrict__ x,
                                                const float* __restrict__ wq,
                                                const float* __restrict__ wk,
                                                const float* __restrict__ wv,
                                                ushort_t* __restrict__ xb,
                                                ushort_t* __restrict__ wqb,
                                                ushort_t* __restrict__ wkb,
                                                ushort_t* __restrict__ wvb) {
  int i = blockIdx.x * 256 + threadIdx.x;   // 0 .. 7*2^20-1
  const float* s; ushort_t* d; int off;
  if (i < (4 << 20)) { s = x; d = xb; off = i; }
  else {
    const int j = i - (4 << 20);
    const int seg = j >> 20;
    off = j & ((1 << 20) - 1);
    s = (seg == 0) ? wq : (seg == 1) ? wk : wv;
    d = (seg == 0) ? wqb : (seg == 1) ? wkb : wvb;
  }
  float4 v = ((const float4*)s)[off];
  ushort4 o; o.x = f2bf(v.x); o.y = f2bf(v.y); o.z = f2bf(v.z); o.w = f2bf(v.w);
  ((ushort4*)d)[off] = o;
}

// ---------------- unified GEMM: C = A[M,K] * B^T, bf16 in, fp32 acc ----------------
// 256x256 tile, 512 threads (8 waves, 2M x 4N), mfma_f32_16x16x32_bf16.
// K pipelined as a ring of 4 sub-tiles of K=32 (A[256][32]+B[256][32] per slot,
// 128 KiB LDS). Per sub-tile: issue 12 ds_read_b128 frags + 4 global_load_lds
// (prefetch sub-tile u+3), then setprio(1) 32 MFMA setprio(0), then ONE
// boundary: sched_barrier; counted s_waitcnt vmcnt(8); s_barrier; sched_barrier.
// [Measured best schedule: r2 = 198us/47% MfmaUtil on proj shape. The two
//  register-pipelined variants (r3/r4) regressed to 231-238us/38% -- the
//  mid-body fragment pre-read structure, not vmcnt slack, was the cost.]
// LDS 16B-part swizzle: physical part p of row r holds global part p ^ ((r>>1)&3),
// applied by pre-swizzling the GLOBAL source (global_load_lds dest stays linear).
// SEG2: B rows come from B0 for k < Kseg, else B1 (same ldb); Kseg % 32 == 0.
struct GZ  { const ushort_t* A; const ushort_t* B0; const ushort_t* B1; void* C; };
struct GZV { GZ z[12]; };

template <bool OUT_BF16, bool SEG2>
__global__ __launch_bounds__(512, 2) void gemm_bt(GZV gz, int lda, int ldb, int K, int Kseg,
                                                  int ldc, float scale) {
  __shared__ ushort_t As[4][256 * 32];   // 4 x 16 KiB
  __shared__ ushort_t Bs[4][256 * 32];   // 4 x 16 KiB
  const GZ g = gz.z[blockIdx.z];

  const int tid  = threadIdx.x;
  const int lane = tid & 63;
  const int wave = tid >> 6;
  const int wm = wave >> 2, wn = wave & 3;           // 2 x 4 wave grid
  const int m0 = blockIdx.y * 256, n0 = blockIdx.x * 256;

  // ---- staging invariants: 1024 chunks of 16B per matrix per sub-tile,
  //      2 rounds of 512 threads. chunk c = tid + j*512: row c>>2, phys part c&3.
  const int r0s = tid >> 2;                          // 0..127 (round 0); round1 = +128
  const int pgs = (tid & 3) ^ ((r0s >> 1) & 3);      // global part (swizzle involution)
  const ushort_t* gA  = g.A  + (size_t)(m0 + r0s) * lda + pgs * 8;
  const ushort_t* gB0 = g.B0 + (size_t)(n0 + r0s) * ldb + pgs * 8;
  const ushort_t* gB1 = SEG2 ? (g.B1 + (size_t)(n0 + r0s) * ldb + pgs * 8) : gB0;
  const size_t rstepA = (size_t)128 * lda;
  const size_t rstepB = (size_t)128 * ldb;
  const int ldsOff = tid * 8;                        // ushort units; 16B per thread

  // ---- loop-invariant fragment read offsets (ushort units)
  const int laneRow = lane & 15, quad = lane >> 4;
  int offA[8], offB[4];
  #pragma unroll
  for (int mi = 0; mi < 8; ++mi) {
    const int row = wm * 128 + mi * 16 + laneRow;
    offA[mi] = row * 32 + ((quad ^ ((row >> 1) & 3)) * 8);
  }
  #pragma unroll
  for (int ni = 0; ni < 4; ++ni) {
    const int row = wn * 64 + ni * 16 + laneRow;
    offB[ni] = row * 32 + ((quad ^ ((row >> 1) & 3)) * 8);
  }

  const int NU = K >> 5;   // number of K=32 sub-tiles

  auto stageA = [&](int u) {
    const int k0 = u << 5;
    ushort_t* dst = &As[u & 3][0];
    __builtin_amdgcn_global_load_lds((const AS1 uint32_t*)(gA + k0),
                                     (AS3 uint32_t*)(dst + ldsOff), 16, 0, 0);
    __builtin_amdgcn_global_load_lds((const AS1 uint32_t*)(gA + rstepA + k0),
                                     (AS3 uint32_t*)(dst + 4096 + ldsOff), 16, 0, 0);
  };
  auto stageB = [&](int u) {
    const int k0 = u << 5;
    ushort_t* dst = &Bs[u & 3][0];
    const ushort_t* src = gB0;
    int kk = k0;
    if (SEG2 && k0 >= Kseg) { src = gB1; kk = k0 - Kseg; }
    __builtin_amdgcn_global_load_lds((const AS1 uint32_t*)(src + kk),
                                     (AS3 uint32_t*)(dst + ldsOff), 16, 0, 0);
    __builtin_amdgcn_global_load_lds((const AS1 uint32_t*)(src + rstepB + kk),
                                     (AS3 uint32_t*)(dst + 4096 + ldsOff), 16, 0, 0);
  };

  f32x4 acc[8][4] = {};

  // ---- prologue: stage sub-tiles 0,1,2 (12 loads); wait sub-tile 0 (8 in flight)
  stageA(0); stageB(0);
  stageA(1); stageB(1);
  stageA(2); stageB(2);
  __builtin_amdgcn_sched_barrier(0);
  asm volatile("s_waitcnt vmcnt(8)" ::: "memory");
  __builtin_amdgcn_s_barrier();
  __builtin_amdgcn_sched_barrier(0);

  for (int u = 0; u < NU; ++u) {
    const ushort_t* Au = &As[u & 3][0];
    const ushort_t* Bu = &Bs[u & 3][0];
    const bool pre = (u + 3) < NU;

    // ---- issue all fragment reads for this sub-tile (compiler interleaves
    //      lgkmcnt-counted waits with the MFMA block below)
    bf16x8 af[8], bf[4];
    #pragma unroll
    for (int mi = 0; mi < 8; ++mi) af[mi] = *(const bf16x8*)(Au + offA[mi]);
    #pragma unroll
    for (int ni = 0; ni < 4; ++ni) bf[ni] = *(const bf16x8*)(Bu + offB[ni]);

    // ---- prefetch sub-tile u+3 (lands 2 sub-tiles from now; vmcnt-counted)
    if (pre) { stageA(u + 3); stageB(u + 3); }

    // ---- 32 independent-acc MFMAs
    __builtin_amdgcn_s_setprio(1);
    #pragma unroll
    for (int mi = 0; mi < 8; ++mi)
      #pragma unroll
      for (int ni = 0; ni < 4; ++ni)
        acc[mi][ni] = __builtin_amdgcn_mfma_f32_16x16x32_bf16(af[mi], bf[ni], acc[mi][ni], 0, 0, 0);
    __builtin_amdgcn_s_setprio(0);

    // ---- single sub-tile boundary: counted wait -> sub-tile u+1 fully staged.
    // Steady state: 8 outstanding loads (sub-tiles u+2, u+3). Tail: drain.
    __builtin_amdgcn_sched_barrier(0);
    if (pre) { asm volatile("s_waitcnt vmcnt(8)" ::: "memory"); }
    else     { asm volatile("s_waitcnt vmcnt(0)" ::: "memory"); }
    __builtin_amdgcn_s_barrier();
    __builtin_amdgcn_sched_barrier(0);
  }

  // ---- epilogue: C/D layout col = lane&15, row = (lane>>4)*4 + reg
  const int col = lane & 15;
  #pragma unroll
  for (int mi = 0; mi < 8; ++mi) {
    #pragma unroll
    for (int ni = 0; ni < 4; ++ni) {
      const int n = n0 + wn * 64 + ni * 16 + col;
      const int mb = m0 + wm * 128 + mi * 16 + quad * 4;
      #pragma unroll
      for (int r = 0; r < 4; ++r) {
        const int m = mb + r;
        const float v = acc[mi][ni][r] * scale;
        if constexpr (OUT_BF16)
          ((ushort_t*)g.C)[(size_t)m * ldc + n] = f2bf(v);
        else
          ((float*)g.C)[(size_t)m * ldc + n] = v;
      }
    }
  }
}

// ---------------- merged: softmax on S0/S1 (y=0,1) + past_v transpose (y=2) --------
// Softmax: in-place row softmax on bf16 S [4096 rows][4096], one block per row.
// Transpose: fp32 [PAST][D] -> bf16 [D][PAST]; 4096 tiles of 64x64 (1024/batch).
// Legal at this point: Kp is dead after S1 (VTp overlays it); PV consumes both.
__global__ __launch_bounds__(256) void sm_trans(const float* __restrict__ pv,
                                                ushort_t* __restrict__ vtp,
                                                ushort_t* __restrict__ Sa,
                                                ushort_t* __restrict__ Sb) {
  if (blockIdx.y == 2) {
    __shared__ float tile[64][65];
    const int t = blockIdx.x;
    const int b = t >> 10;                       // 1024 tiles per batch
    const int r0 = (t & 31) * 64, c0 = ((t >> 5) & 31) * 64;
    const float* src = pv + (size_t)b * PAST * D_;
    ushort_t* dst = vtp + (size_t)b * D_ * PAST;
    const int tid = threadIdx.x;
    const int rr = tid >> 4, cc = (tid & 15) * 4;
    #pragma unroll
    for (int it = 0; it < 4; ++it) {
      int r = rr + it * 16;
      float4 v = *(const float4*)(src + (size_t)(r0 + r) * D_ + c0 + cc);
      tile[r][cc] = v.x; tile[r][cc + 1] = v.y; tile[r][cc + 2] = v.z; tile[r][cc + 3] = v.w;
    }
    __syncthreads();
    const int cw = tid >> 4, rw = (tid & 15) * 4;
    #pragma unroll
    for (int it = 0; it < 4; ++it) {
      int c = cw + it * 16;
      ushort4 o;
      o.x = f2bf(tile[rw][c]);     o.y = f2bf(tile[rw + 1][c]);
      o.z = f2bf(tile[rw + 2][c]); o.w = f2bf(tile[rw + 3][c]);
      *(ushort4*)(dst + (size_t)(c0 + c) * PAST + r0 + rw) = o;
    }
    return;
  }

  ushort_t* S = blockIdx.y ? Sb : Sa;
  const int row = blockIdx.x, tid = threadIdx.x;
  const int lane = tid & 63, wave = tid >> 6;
  ushort_t* s = S + (size_t)row * LK;

  float e[16];
  float m = -1e30f;
  #pragma unroll
  for (int i = 0; i < 2; ++i) {
    uint4 raw = *(const uint4*)(s + i * 2048 + tid * 8);
    const uint32_t u[4] = { raw.x, raw.y, raw.z, raw.w };
    #pragma unroll
    for (int j = 0; j < 4; ++j) {
      union { uint32_t u; float f; } lo, hi;
      lo.u = u[j] << 16;
      hi.u = u[j] & 0xFFFF0000u;
      e[i * 8 + j * 2] = lo.f;
      e[i * 8 + j * 2 + 1] = hi.f;
      m = fmaxf(m, fmaxf(lo.f, hi.f));
    }
  }
  #pragma unroll
  for (int off = 32; off > 0; off >>= 1) m = fmaxf(m, __shfl_xor(m, off));
  __shared__ float redm[4], reds[4];
  if (lane == 0) redm[wave] = m;
  __syncthreads();
  m = fmaxf(fmaxf(redm[0], redm[1]), fmaxf(redm[2], redm[3]));

  float sum = 0.f;
  #pragma unroll
  for (int i = 0; i < 16; ++i) { e[i] = __expf(e[i] - m); sum += e[i]; }
  #pragma unroll
  for (int off = 32; off > 0; off >>= 1) sum += __shfl_xor(sum, off);
  if (lane == 0) reds[wave] = sum;
  __syncthreads();
  sum = reds[0] + reds[1] + reds[2] + reds[3];
  const float inv = 1.0f / sum;

  #pragma unroll
  for (int i = 0; i < 2; ++i) {
    uint4 o;
    uint32_t* po = &o.x;
    #pragma unroll
    for (int j = 0; j < 4; ++j) {
      uint32_t lo = f2bf(e[i * 8 + j * 2] * inv);
      uint32_t hi = f2bf(e[i * 8 + j * 2 + 1] * inv);
      po[j] = lo | (hi << 16);
    }
    *(uint4*)(s + i * 2048 + tid * 8) = o;
  }
}

// ---------------- launch ----------------
extern "C" void kernel_launch(void* const* d_in, const int* in_sizes, int n_in,
                              void* d_out, int out_size, void* d_ws, size_t ws_size,
                              hipStream_t stream) {
  const float* x      = (const float*)d_in[0];
  const float* past_k = (const float*)d_in[1];
  const float* past_v = (const float*)d_in[2];
  const float* Wq     = (const float*)d_in[3];
  const float* Wk     = (const float*)d_in[4];
  const float* Wv     = (const float*)d_in[5];
  float* out = (float*)d_out;

  const size_t MB = 1024 * 1024;
  const size_t NEED = 160 * MB;
  if (ws_size < NEED) {
    diag_fill<<<(out_size / 4 + 255) / 256, 256, 0, stream>>>(out, out_size / 4,
                                                              (float)((double)ws_size * 1e-9));
    return;
  }

  char* ws = (char*)d_ws;
  // Layout (MB):
  //   0-16  : Q pair0 (b0@0, b1@8)         [dead after S-gemm pair0]
  //  16-32  : Knew pair0 (b0@16, b1@24)    [dead after S-gemm pair0]
  //  32-48  : Q pair1 (b2@32, b3@40)       [dead after S-gemm pair1]
  //  48-64  : Knew pair1 (b2@48, b3@56)    [dead after S-gemm pair1]
  //  64-96  : VTnew all (b@64+8b), [D][QLEN]
  //  96-160 : scratch:
  //     phase A : xb@96 (32), Wq@128, Wk@136, Wv@144
  //     then    : Kp all @96 (32, [PAST][D] per b)
  //     then    : S0 (pair0) @128 (32, bf16 [4096][4096])
  //     then    : S1 (pair1) @0   (32, over dead Q/Kn pair0)
  //     then    : VTp all @96 (32, [D][PAST] per b, over dead Kp)
  ushort_t* Qp[4]  = { (ushort_t*)(ws),            (ushort_t*)(ws + 8  * MB),
                       (ushort_t*)(ws + 32 * MB),  (ushort_t*)(ws + 40 * MB) };
  ushort_t* Knp[4] = { (ushort_t*)(ws + 16 * MB),  (ushort_t*)(ws + 24 * MB),
                       (ushort_t*)(ws + 48 * MB),  (ushort_t*)(ws + 56 * MB) };
  ushort_t* VTn = (ushort_t*)(ws + 64 * MB);   // + b*8MB
  ushort_t* xb  = (ushort_t*)(ws + 96 * MB);   // + b*8MB
  ushort_t* Wqb = (ushort_t*)(ws + 128 * MB);
  ushort_t* Wkb = (ushort_t*)(ws + 136 * MB);
  ushort_t* Wvb = (ushort_t*)(ws + 144 * MB);
  ushort_t* Kp  = (ushort_t*)(ws + 96 * MB);   // + b*8MB (after xb dead)
  ushort_t* S0  = (ushort_t*)(ws + 128 * MB);  // rows 0-2047: b0, 2048-4095: b1
  ushort_t* S1  = (ushort_t*)(ws);             // rows 0-2047: b2, 2048-4095: b3
  ushort_t* VTp = (ushort_t*)(ws + 96 * MB);   // + b*8MB (after Kp dead)

  const size_t SLICE = (size_t)QLEN * D_;      // 4M elements = 8 MB bf16

  // ---- phase A: all input casts in ONE launch (x + Wq + Wk + Wv) ----
  cast_pre<<<(7 << 20) / 256, 256, 0, stream>>>(x, Wq, Wk, Wv, xb, Wqb, Wkb, Wvb);

  // ---- all projections in one Z=12 launch: Q, Knew, VTnew ----
  {
    GZV g{};
    for (int b = 0; b < B_; ++b) {
      const ushort_t* xbb = xb + (size_t)b * SLICE;
      g.z[b]     = { xbb, Wqb, Wqb, Qp[b] };                      // Q_b [t][d]
      g.z[4 + b] = { xbb, Wkb, Wkb, Knp[b] };                     // Kn_b [t][d]
      g.z[8 + b] = { Wvb, xbb, xbb, VTn + (size_t)b * SLICE };    // VTn_b [d][t]
    }
    gemm_bt<true, false><<<dim3(8, 8, 12), 512, 0, stream>>>(g, D_, D_, D_, D_, D_, 1.0f);
  }

  // ---- cast past_k (all batches) ----
  cast_f32_bf16<<<(B_ * (size_t)PAST * D_ / 4) / 256, 256, 0, stream>>>(
      past_k, Kp, B_ * PAST * D_ / 4);

  const float sc = 0.022097086912079608f;  // 1/sqrt(2048)

  // ---- S pair0 (b0,b1): Z=4, bf16 out into S0 ----
  {
    GZV g{};
    for (int j = 0; j < 2; ++j) {
      const int b = j;
      ushort_t* Sb = S0 + (size_t)j * QLEN * LK;
      g.z[2 * j]     = { Qp[b], Kp + (size_t)b * SLICE,  Kp + (size_t)b * SLICE,  Sb };
      g.z[2 * j + 1] = { Qp[b], Knp[b],                  Knp[b],                  Sb + PAST };
    }
    gemm_bt<true, false><<<dim3(8, 8, 4), 512, 0, stream>>>(g, D_, D_, D_, D_, LK, sc);
  }
  // ---- S pair1 (b2,b3): Z=4, bf16 out into S1 (over dead Q/Kn pair0) ----
  {
    GZV g{};
    for (int j = 0; j < 2; ++j) {
      const int b = 2 + j;
      ushort_t* Sb = S1 + (size_t)j * QLEN * LK;
      g.z[2 * j]     = { Qp[b], Kp + (size_t)b * SLICE,  Kp + (size_t)b * SLICE,  Sb };
      g.z[2 * j + 1] = { Qp[b], Knp[b],                  Knp[b],                  Sb + PAST };
    }
    gemm_bt<true, false><<<dim3(8, 8, 4), 512, 0, stream>>>(g, D_, D_, D_, D_, LK, sc);
  }

  // ---- merged: softmax (S0,S1) + transpose-cast past_v -> VTp (over dead Kp) ----
  sm_trans<<<dim3(4096, 3), 256, 0, stream>>>(past_v, VTp, S0, S1);

  // ---- PV: Z=4, 2-segment K (VTp then VTn), fp32 out to d_out ----
  {
    GZV g{};
    const ushort_t* Pb[4] = { S0, S0 + (size_t)QLEN * LK, S1, S1 + (size_t)QLEN * LK };
    for (int b = 0; b < B_; ++b)
      g.z[b] = { Pb[b], VTp + (size_t)b * SLICE, VTn + (size_t)b * SLICE,
                 out + (size_t)b * QLEN * D_ };
    gemm_bt<false, true><<<dim3(8, 8, 4), 512, 0, stream>>>(g, LK, PAST, LK, PAST, D_, 1.0f);
  }
}